// Round 10
// baseline (490.607 us; speedup 1.0000x reference)
//
#include <hip/hip_runtime.h>

typedef unsigned short u16;
typedef unsigned int   u32;
typedef short bf16x8 __attribute__((ext_vector_type(8)));
typedef float f32x2  __attribute__((ext_vector_type(2)));
typedef float f32x4  __attribute__((ext_vector_type(4)));
typedef float f32x16 __attribute__((ext_vector_type(16)));

#define NB  32
#define NQ  1024
#define GS  1024
#define NH  8
#define SCQ (0.25f * 1.4426950408889634f)   /* 1/sqrt(16) * log2(e) */
#define MBIG (-1.0e30f)

#define MFMA16(a, b, c) __builtin_amdgcn_mfma_f32_16x16x32_bf16(a, b, c, 0, 0, 0)
#define MFMA32(a, b, c) __builtin_amdgcn_mfma_f32_32x32x16_bf16(a, b, c, 0, 0, 0)

__device__ __forceinline__ u16 f2bf(float f) {  // RNE float->bf16 bits
    u32 u = __float_as_uint(f);
    return (u16)((u + 0x7fffu + ((u >> 16) & 1u)) >> 16);
}
// packed round-half-up: result = bf(a) | bf(b)<<16, 3 VALU ops via v_perm_b32
__device__ __forceinline__ u32 pk2bf(float a, float b) {
    u32 ua = __float_as_uint(a) + 0x8000u;
    u32 ub = __float_as_uint(b) + 0x8000u;
    return __builtin_amdgcn_perm(ub, ua, 0x07060302u);  // bytes [b3 b2 a3 a2]
}

// ---------------------------------------------------------------------------
// MFMA GEMM v7: C[128x128] = A[128x128] * W^T, K=128.
// NO A-LDS staging: each lane loads its MFMA A-fragments DIRECTLY from
// global (2x float4 per frag) and converts fp32->bf16 in-register. Only W
// goes through LDS (34.8 KB); the store-epilogue buffer ALIASES Ws.
// MODE 0: bf16 out row-major.
// MODE 2: bf16 out transposed per batch with slot permutation sigma per
//         16-token group (swap quads 1<->2): places key rows so flash's
//         in-register P words feed PV's MFMA32 B operand directly.
// ---------------------------------------------------------------------------
template <int MODE>
__device__ __forceinline__ void mgemm(const float* __restrict__ Ain,
                                      const float* __restrict__ Wraw,
                                      float wsc,
                                      u16* __restrict__ outb,
                                      u16* Ws, int row0) {
    const int t    = threadIdx.x;
    const int wv   = t >> 6;
    const int lane = t & 63;
    const int quad = lane >> 4;
    const int c    = lane & 15;

    // W stage: Ws[col*136 + k] = bf16(W[h][k][e]*wsc), col = 16h+e.
#pragma unroll
    for (int g0 = 0; g0 < 2048; g0 += 256) {
        int idx  = g0 + t;
        int hk   = idx >> 1, half = idx & 1;
        int k    = hk & 127;
        int col0 = (hk >> 7) * 16 + half * 8;
        const float4* wp = (const float4*)&Wraw[hk * 16 + half * 8];
        float4 w0 = wp[0], w1 = wp[1];
        Ws[(col0 + 0) * 136 + k] = f2bf(w0.x * wsc);
        Ws[(col0 + 1) * 136 + k] = f2bf(w0.y * wsc);
        Ws[(col0 + 2) * 136 + k] = f2bf(w0.z * wsc);
        Ws[(col0 + 3) * 136 + k] = f2bf(w0.w * wsc);
        Ws[(col0 + 4) * 136 + k] = f2bf(w1.x * wsc);
        Ws[(col0 + 5) * 136 + k] = f2bf(w1.y * wsc);
        Ws[(col0 + 6) * 136 + k] = f2bf(w1.z * wsc);
        Ws[(col0 + 7) * 136 + k] = f2bf(w1.w * wsc);
    }

    // A fragments: rows wv*32+c and wv*32+16+c, k-octet kt*32+quad*8.
    const float* a0p = &Ain[(size_t)(row0 + wv * 32 + c) * 128];
    const float* a1p = &Ain[(size_t)(row0 + wv * 32 + 16 + c) * 128];
    bf16x8 af0[4], af1[4];
#pragma unroll
    for (int kt = 0; kt < 4; ++kt) {
        int k0 = kt * 32 + quad * 8;
        float4 x0 = *(const float4*)&a0p[k0];
        float4 x1 = *(const float4*)&a0p[k0 + 4];
        float4 y0 = *(const float4*)&a1p[k0];
        float4 y1 = *(const float4*)&a1p[k0 + 4];
        int4 p0, p1;
        p0.x = (int)pk2bf(x0.x, x0.y);  p0.y = (int)pk2bf(x0.z, x0.w);
        p0.z = (int)pk2bf(x1.x, x1.y);  p0.w = (int)pk2bf(x1.z, x1.w);
        p1.x = (int)pk2bf(y0.x, y0.y);  p1.y = (int)pk2bf(y0.z, y0.w);
        p1.z = (int)pk2bf(y1.x, y1.y);  p1.w = (int)pk2bf(y1.z, y1.w);
        __builtin_memcpy(&af0[kt], &p0, 16);
        __builtin_memcpy(&af1[kt], &p1, 16);
    }
    __syncthreads();                     // Ws ready

    const f32x4 zf = {0.f, 0.f, 0.f, 0.f};
    f32x4 acc[2][8];
#pragma unroll
    for (int s = 0; s < 2; ++s)
#pragma unroll
        for (int j = 0; j < 8; ++j) acc[s][j] = zf;

#pragma unroll
    for (int kt = 0; kt < 4; ++kt) {
#pragma unroll
        for (int j = 0; j < 8; ++j) {
            bf16x8 bfr = *(const bf16x8*)&Ws[(j * 16 + c) * 136 + kt * 32 + quad * 8];
            acc[0][j] = MFMA16(af0[kt], bfr, acc[0][j]);
            acc[1][j] = MFMA16(af1[kt], bfr, acc[1][j]);
        }
    }

    // ---- epilogue via LDS (aliases Ws): scatter bf16, coalesced int4 out ----
    __syncthreads();                     // all Ws reads complete
    u16* Os = Ws;
#pragma unroll
    for (int s = 0; s < 2; ++s)
#pragma unroll
        for (int j = 0; j < 8; ++j)
#pragma unroll
            for (int r = 0; r < 4; ++r) {
                int lrow = wv * 32 + s * 16 + quad * 4 + r;
                int col  = j * 16 + c;
                u16 v = f2bf(acc[s][j][r]);
                if (MODE == 0) {
                    Os[lrow * 136 + col] = v;
                } else {
                    int u   = lrow & 15;
                    int sw  = ((u >> 2) ^ (u >> 3)) & 1;     // sigma: swap quads 1<->2
                    int tbp = lrow ^ (sw ? 12 : 0);
                    Os[col * 136 + tbp] = v;
                }
            }
    __syncthreads();

    if (MODE == 0) {
#pragma unroll
        for (int it = 0; it < 8; ++it) {
            int chunk = it * 256 + t;
            int lrow = chunk >> 4, c0 = (chunk & 15) * 8;
            *(int4*)&outb[(size_t)(row0 + lrow) * 128 + c0] =
                *(const int4*)&Os[lrow * 136 + c0];
        }
    } else {
        int bI = row0 >> 10, tb0 = row0 & 1023;
#pragma unroll
        for (int it = 0; it < 8; ++it) {
            int chunk = it * 256 + t;
            int col = chunk >> 4, t0 = (chunk & 15) * 8;
            *(int4*)&outb[(size_t)bI * (128 * 1024) + (size_t)col * 1024 + tb0 + t0] =
                *(const int4*)&Os[col * 136 + t0];
        }
    }
}

__global__ __launch_bounds__(256, 3) void proj_mfma(const float* __restrict__ q,
                                                    const float* __restrict__ h,
                                                    const float* __restrict__ Wq,
                                                    const float* __restrict__ Wk,
                                                    const float* __restrict__ Wv,
                                                    const float* __restrict__ Wout,
                                                    u16* __restrict__ Qb,
                                                    u16* __restrict__ Kb,
                                                    u16* __restrict__ Vtg,
                                                    u16* __restrict__ Wob) {
    __shared__ u16 Ws[128 * 136];
    int y = blockIdx.y;
    if (y == 3) {
        // Wob prep: [d][he] = Wout[he>>4][he&15][d], blocks x<64
        if (blockIdx.x < 64) {
            int i = blockIdx.x * 256 + threadIdx.x;    // 0..16383
            int d = i >> 7, he = i & 127;
            Wob[i] = f2bf(Wout[(he >> 4) * 2048 + (he & 15) * 128 + d]);
        }
        return;
    }
    int row0 = blockIdx.x * 128;
    if (y == 0)      mgemm<0>(q, Wq, SCQ,  Qb,  Ws, row0);
    else if (y == 1) mgemm<0>(h, Wk, 1.0f, Kb,  Ws, row0);
    else             mgemm<2>(h, Wv, 1.0f, Vtg, Ws, row0);
}

// ---------------------------------------------------------------------------
// MFMA flash attention + fused out-projection, v10 = v9 + QBLK 32->64.
// Round-9 audit: MFMA 11us, VALU+trans 36us, HBM 16us of a 94us kernel —
// the rest is per-tile sync/staging critical path. v10 amortizes it: each
// K-tile now serves TWO q-groups (64 rows). Constant per tile: K/V staging,
// kf/vf ds_reads (shared across groups), 2 barriers, prefetch drain.
// Doubled per tile: score/PV MFMA, exp, pack (the useful work).
// Also: 512 blocks = exactly 2/CU resident -> single generation, no tail;
// K/V L2 traffic halves. LDS: Kt 17408 (rows reused as 64-row Hs) +
// Vtt 18432 + Mf 64*68*4 = 17408  -> 53248 B -> 2 blocks/CU at (512,4).
// ---------------------------------------------------------------------------
__global__ __launch_bounds__(512, 4) void flash_mfma(const u16* __restrict__ Qb,
                                                     const u16* __restrict__ Kb,
                                                     const u16* __restrict__ Vtg,
                                                     const int* __restrict__ mask,
                                                     const u16* __restrict__ Wob,
                                                     float* __restrict__ out) {
    __shared__ u16 Kt[64 * 136];        // [key][dim]; reused as 64-row Hs
    __shared__ u16 Vtt[128 * 72];       // [dim][slot], sigma-permuted slots
    __shared__ float Mf[64 * 68];       // mask addend [q 0..63][key 0..63]

    const int b    = blockIdx.x;
    const int q0   = blockIdx.y * 64;
    const int t    = threadIdx.x;
    const int hh   = t >> 6;
    const int lane = t & 63;
    const int quad = lane >> 4;         // 0..3
    const int c    = lane & 15;
    const int qq   = lane & 31;
    const int hi   = lane >> 5;

    // Q fragments for both q-groups
    bf16x8 qf[2];
#pragma unroll
    for (int g = 0; g < 2; ++g)
        qf[g] = *(const bf16x8*)&Qb[((size_t)b * NQ + q0 + g * 32 + qq) * 128 +
                                    hh * 16 + hi * 8];

    f32x16 O32[2];
#pragma unroll
    for (int g = 0; g < 2; ++g)
#pragma unroll
        for (int r = 0; r < 16; ++r) O32[g][r] = 0.f;
    float lsum[2] = {0.f, 0.f};

    // staging indices
    const int skey = t >> 4;            // K: key 0..31 (+32), dim octet (t&15)*8
    const int sd0  = (t & 15) * 8;
    const int vdim = t >> 2;            // V: dim 0..127, slot octet (t&3)*8 (+32)
    const int vs0  = (t & 3) * 8;
    const int mrow = t >> 4;            // M: q-row 0..31 (+32), key pair (t&15)*2
    const int mk0  = (t & 15) * 2;

    const u16* Kptr = &Kb[((size_t)b * GS + skey) * 128 + sd0];
    const u16* Vptr = &Vtg[(size_t)b * (128 * 1024) + (size_t)vdim * 1024 + vs0];
    const int* Mptr0 = &mask[((size_t)b * NQ + q0 + mrow) * GS + mk0];
    const int* Mptr1 = Mptr0 + (size_t)32 * GS;

    int4 kreg0 = *(const int4*)Kptr;
    int4 kreg1 = *(const int4*)(Kptr + 32 * 128);
    int4 vreg0 = *(const int4*)Vptr;
    int4 vreg1 = *(const int4*)(Vptr + 32);
    int2 mreg0 = *(const int2*)Mptr0;
    int2 mreg1 = *(const int2*)(Mptr0 + 32);
    int2 mreg2 = *(const int2*)Mptr1;
    int2 mreg3 = *(const int2*)(Mptr1 + 32);

    for (int g0 = 0; g0 < GS; g0 += 64) {
        __syncthreads();
        *(int4*)&Kt[skey * 136 + sd0]        = kreg0;
        *(int4*)&Kt[(32 + skey) * 136 + sd0] = kreg1;
        *(int4*)&Vtt[vdim * 72 + vs0]        = vreg0;
        *(int4*)&Vtt[vdim * 72 + 32 + vs0]   = vreg1;
        f32x2 mm0, mm1, mm2, mm3;
        mm0.x = mreg0.x ? MBIG : 0.f;  mm0.y = mreg0.y ? MBIG : 0.f;
        mm1.x = mreg1.x ? MBIG : 0.f;  mm1.y = mreg1.y ? MBIG : 0.f;
        mm2.x = mreg2.x ? MBIG : 0.f;  mm2.y = mreg2.y ? MBIG : 0.f;
        mm3.x = mreg3.x ? MBIG : 0.f;  mm3.y = mreg3.y ? MBIG : 0.f;
        *(f32x2*)&Mf[mrow * 68 + mk0]             = mm0;
        *(f32x2*)&Mf[mrow * 68 + 32 + mk0]        = mm1;
        *(f32x2*)&Mf[(32 + mrow) * 68 + mk0]      = mm2;
        *(f32x2*)&Mf[(32 + mrow) * 68 + 32 + mk0] = mm3;
        __syncthreads();

        if (g0 + 64 < GS) {
            Kptr += 64 * 128;
            kreg0 = *(const int4*)Kptr;
            kreg1 = *(const int4*)(Kptr + 32 * 128);
            Vptr += 64;
            vreg0 = *(const int4*)Vptr;
            vreg1 = *(const int4*)(Vptr + 32);
            Mptr0 += 64;  Mptr1 += 64;
            mreg0 = *(const int2*)Mptr0;
            mreg1 = *(const int2*)(Mptr0 + 32);
            mreg2 = *(const int2*)Mptr1;
            mreg3 = *(const int2*)(Mptr1 + 32);
        }

        // shared-per-tile fragments
        bf16x8 kf0 = *(const bf16x8*)&Kt[qq * 136 + hh * 16 + hi * 8];
        bf16x8 kf1 = *(const bf16x8*)&Kt[(32 + qq) * 136 + hh * 16 + hi * 8];
        bf16x8 vf0 = *(const bf16x8*)&Vtt[(hh * 16 + c) * 72 + hi * 8];
        bf16x8 vf1 = *(const bf16x8*)&Vtt[(hh * 16 + c) * 72 + 16 + hi * 8];
        bf16x8 vf2 = *(const bf16x8*)&Vtt[(hh * 16 + c) * 72 + 32 + hi * 8];
        bf16x8 vf3 = *(const bf16x8*)&Vtt[(hh * 16 + c) * 72 + 48 + hi * 8];

#pragma unroll
        for (int g = 0; g < 2; ++g) {
            const float* mf = &Mf[(g * 32 + qq) * 68];
            // chunk 0: keys 0..31
            {
                f32x16 c0;
#pragma unroll
                for (int blk = 0; blk < 4; ++blk) {
                    f32x4 m0 = *(const f32x4*)&mf[8 * blk + 4 * hi];
                    c0[4 * blk + 0] = m0.x;  c0[4 * blk + 1] = m0.y;
                    c0[4 * blk + 2] = m0.z;  c0[4 * blk + 3] = m0.w;
                }
                f32x16 s0 = MFMA32(kf0, qf[g], c0);
#pragma unroll
                for (int r = 0; r < 16; ++r) s0[r] = __builtin_amdgcn_exp2f(s0[r]);
                lsum[g] += ((s0[0] + s0[1]) + (s0[2] + s0[3])) +
                           ((s0[4] + s0[5]) + (s0[6] + s0[7])) +
                           (((s0[8] + s0[9]) + (s0[10] + s0[11])) +
                            ((s0[12] + s0[13]) + (s0[14] + s0[15])));
                int4 pa, pb;
                pa.x = (int)pk2bf(s0[0],  s0[1]);  pa.y = (int)pk2bf(s0[2],  s0[3]);
                pa.z = (int)pk2bf(s0[4],  s0[5]);  pa.w = (int)pk2bf(s0[6],  s0[7]);
                pb.x = (int)pk2bf(s0[8],  s0[9]);  pb.y = (int)pk2bf(s0[10], s0[11]);
                pb.z = (int)pk2bf(s0[12], s0[13]); pb.w = (int)pk2bf(s0[14], s0[15]);
                bf16x8 p0, p1;
                __builtin_memcpy(&p0, &pa, 16);
                __builtin_memcpy(&p1, &pb, 16);
                O32[g] = MFMA32(vf0, p0, O32[g]);
                O32[g] = MFMA32(vf1, p1, O32[g]);
            }
            // chunk 1: keys 32..63
            {
                f32x16 c1;
#pragma unroll
                for (int blk = 0; blk < 4; ++blk) {
                    f32x4 m1 = *(const f32x4*)&mf[32 + 8 * blk + 4 * hi];
                    c1[4 * blk + 0] = m1.x;  c1[4 * blk + 1] = m1.y;
                    c1[4 * blk + 2] = m1.z;  c1[4 * blk + 3] = m1.w;
                }
                f32x16 s1 = MFMA32(kf1, qf[g], c1);
#pragma unroll
                for (int r = 0; r < 16; ++r) s1[r] = __builtin_amdgcn_exp2f(s1[r]);
                lsum[g] += ((s1[0] + s1[1]) + (s1[2] + s1[3])) +
                           ((s1[4] + s1[5]) + (s1[6] + s1[7])) +
                           (((s1[8] + s1[9]) + (s1[10] + s1[11])) +
                            ((s1[12] + s1[13]) + (s1[14] + s1[15])));
                int4 pa, pb;
                pa.x = (int)pk2bf(s1[0],  s1[1]);  pa.y = (int)pk2bf(s1[2],  s1[3]);
                pa.z = (int)pk2bf(s1[4],  s1[5]);  pa.w = (int)pk2bf(s1[6],  s1[7]);
                pb.x = (int)pk2bf(s1[8],  s1[9]);  pb.y = (int)pk2bf(s1[10], s1[11]);
                pb.z = (int)pk2bf(s1[12], s1[13]); pb.w = (int)pk2bf(s1[14], s1[15]);
                bf16x8 p2, p3;
                __builtin_memcpy(&p2, &pa, 16);
                __builtin_memcpy(&p3, &pb, 16);
                O32[g] = MFMA32(vf2, p2, O32[g]);
                O32[g] = MFMA32(vf3, p3, O32[g]);
            }
        }
    }

    // per-lane q-row denominators, heads -> Hs (aliases Kt, 64 rows)
    __syncthreads();                    // all Kt/Vtt reads done
    u16* Hs = Kt;
#pragma unroll
    for (int g = 0; g < 2; ++g) {
        float l = lsum[g] + __shfl_xor(lsum[g], 32);
        float rl = (l > 0.f) ? 1.f / l : 0.f;
        u32 h0 = pk2bf(O32[g][0] * rl, O32[g][1] * rl);
        u32 h1 = pk2bf(O32[g][2] * rl, O32[g][3] * rl);
        u32 h2 = pk2bf(O32[g][4] * rl, O32[g][5] * rl);
        u32 h3 = pk2bf(O32[g][6] * rl, O32[g][7] * rl);
        int2 ha; ha.x = (int)h0; ha.y = (int)h1;
        int2 hb; hb.x = (int)h2; hb.y = (int)h3;
        *(int2*)&Hs[(g * 32 + qq) * 136 + hh * 16 + 4 * hi]     = ha;
        *(int2*)&Hs[(g * 32 + qq) * 136 + hh * 16 + 8 + 4 * hi] = hb;
    }
    __syncthreads();

    // fused out-projection: wave hh computes out cols hh*16..+15, 64 rows
    const f32x4 zf = {0.f, 0.f, 0.f, 0.f};
    f32x4 oacc[4] = {zf, zf, zf, zf};
#pragma unroll
    for (int kt = 0; kt < 4; ++kt) {
        bf16x8 bfr = *(const bf16x8*)&Wob[(hh * 16 + c) * 128 + kt * 32 + quad * 8];
#pragma unroll
        for (int s = 0; s < 4; ++s) {
            bf16x8 af = *(const bf16x8*)&Hs[(s * 16 + c) * 136 + kt * 32 + quad * 8];
            oacc[s] = MFMA16(af, bfr, oacc[s]);
        }
    }
#pragma unroll
    for (int s = 0; s < 4; ++s)
#pragma unroll
        for (int r = 0; r < 4; ++r)
            out[((size_t)b * NQ + q0 + s * 16 + quad * 4 + r) * 128 + hh * 16 + c] =
                oacc[s][r];
}

extern "C" void kernel_launch(void* const* d_in, const int* in_sizes, int n_in,
                              void* d_out, int out_size, void* d_ws, size_t ws_size,
                              hipStream_t stream) {
    const float* q    = (const float*)d_in[0];
    const float* h    = (const float*)d_in[1];
    const int*   mask = (const int*)d_in[2];
    const float* Wq   = (const float*)d_in[3];
    const float* Wk   = (const float*)d_in[4];
    const float* Wv   = (const float*)d_in[5];
    const float* Wout = (const float*)d_in[6];
    float* out = (float*)d_out;

    const size_t NTOK = (size_t)NB * NQ;     // 32768
    u16* Qb  = (u16*)d_ws;                   // 8 MB each
    u16* Kb  = Qb + NTOK * 128;
    u16* Vtg = Kb + NTOK * 128;              // V^T per batch, sigma-permuted slots
    u16* Wob = Vtg + NTOK * 128;             // prepped Wout, 32 KB

    proj_mfma<<<dim3(256, 4), 256, 0, stream>>>(q, h, Wq, Wk, Wv, Wout,
                                                Qb, Kb, Vtg, Wob);
    flash_mfma<<<dim3(NB, NQ / 64), 512, 0, stream>>>(Qb, Kb, Vtg, mask,
                                                      Wob, out);
}